// Round 7
// baseline (209.954 us; speedup 1.0000x reference)
//
#include <hip/hip_runtime.h>

// Problem constants: B=2, S=4096, H=8, DH=64, D=512, M = B*S = 8192.
#define LOG2E 1.44269504088896340736f

typedef unsigned short u16;
typedef short s16x4 __attribute__((ext_vector_type(4)));
typedef __bf16 bf16x4_t __attribute__((ext_vector_type(4)));
typedef __bf16 bf16x8_t __attribute__((ext_vector_type(8)));
typedef float f32x4_t __attribute__((ext_vector_type(4)));

__device__ __forceinline__ u16 f2bf(float f) {
  union { float f; unsigned int u; } v;
  v.f = f;
  unsigned int u = v.u;
  u += 0x7fffu + ((u >> 16) & 1u);
  return (u16)(u >> 16);
}

__device__ __forceinline__ f32x4_t mfma16(bf16x8_t a, bf16x8_t b, f32x4_t c) {
  return __builtin_amdgcn_mfma_f32_16x16x32_bf16(a, b, c, 0, 0, 0);
}
// 16x16x16 bf16 (A/B as 4 x i16 bit-patterns)
__device__ __forceinline__ f32x4_t mfma16x16(s16x4 a, s16x4 b, f32x4_t c) {
  return __builtin_amdgcn_mfma_f32_16x16x16bf16_1k(a, b, c, 0, 0, 0);
}

// async 16B global -> LDS (dest = wave-uniform base + lane*16)
__device__ __forceinline__ void gl_lds16(const u16* g, u16* l) {
  __builtin_amdgcn_global_load_lds(
      (const __attribute__((address_space(1))) unsigned int*)g,
      (__attribute__((address_space(3))) unsigned int*)l, 16, 0, 0);
}

// ---------------- cast fp32 -> bf16 (Wq pre-scaled by 0.125*log2e) ----------------
__global__ __launch_bounds__(256) void cast_all_kernel(
    const float* __restrict__ x, const float* __restrict__ wq, const float* __restrict__ wk,
    const float* __restrict__ wv, const float* __restrict__ wo,
    u16* __restrict__ xb, u16* __restrict__ wqb, u16* __restrict__ wkb,
    u16* __restrict__ wvb, u16* __restrict__ wob) {
  const int NX = 2 * 4096 * 512;
  const int NW = 512 * 512;
  int i = (blockIdx.x * 256 + threadIdx.x) * 4;
  const float* src; u16* dst; int off; float scale = 1.f;
  if (i < NX)               { src = x;  dst = xb;  off = i; }
  else if (i < NX + NW)     { src = wq; dst = wqb; off = i - NX; scale = 0.125f * LOG2E; }
  else if (i < NX + 2 * NW) { src = wk; dst = wkb; off = i - NX - NW; }
  else if (i < NX + 3 * NW) { src = wv; dst = wvb; off = i - NX - 2 * NW; }
  else                      { src = wo; dst = wob; off = i - NX - 3 * NW; }
  float4 f = *(const float4*)(src + off);
  unsigned int lo = (unsigned int)f2bf(f.x * scale) | ((unsigned int)f2bf(f.y * scale) << 16);
  unsigned int hi = (unsigned int)f2bf(f.z * scale) | ((unsigned int)f2bf(f.w * scale) << 16);
  uint2 o; o.x = lo; o.y = hi;
  *(uint2*)(dst + off) = o;
}

// ---------------- GEMM: C[M,N] = A[M,512] @ Bt[N,512]^T (both bf16, K-contig) ----------------
// MODE 0: bf16 row-major C. MODE 1: V^T store. MODE 2: fp32 + bias.
// BK=64, LDS double-buffer, global_load_lds staging (XOR chunk swizzle),
// single barrier per K-step, prefetch issued right after the barrier.
template <int MODE>
__device__ __forceinline__ void gemm_core(const u16* __restrict__ A, const u16* __restrict__ Bt,
                                          void* __restrict__ Cout, const float* __restrict__ bias,
                                          int Mbase, int Nbase) {
  __shared__ __align__(16) u16 As[2][128 * 64];   // rows of 64 u16, 8 chunks, slot s = chunk s^(row&7)
  __shared__ __align__(16) u16 Bs[2][128 * 64];
  const int t = threadIdx.x;
  const int wave = t >> 6, lane = t & 63;
  const int r = lane & 15, qd = lane >> 4;
  const int wm = wave & 1, wn = wave >> 1;

  const int rr = lane >> 3;            // 0..7 (row within 8-row group)
  const int cc = (lane & 7) ^ rr;      // swizzled source chunk
  const u16* pa = A  + (Mbase + wave * 32 + rr) * 512 + cc * 8;
  const u16* pb = Bt + (Nbase + wave * 32 + rr) * 512 + cc * 8;

  const int sw = r & 7;
  const int ck0 = (qd ^ sw) * 8;
  const int ck1 = ((qd + 4) ^ sw) * 8;

  f32x4_t acc[4][4];
#pragma unroll
  for (int i = 0; i < 4; i++)
#pragma unroll
    for (int j = 0; j < 4; j++) { f32x4_t z = {0.f, 0.f, 0.f, 0.f}; acc[i][j] = z; }

  // prologue: tile 0 -> buf 0
#pragma unroll
  for (int i = 0; i < 4; i++) {
    gl_lds16(pa + i * 8 * 512, &As[0][(wave * 32 + i * 8) * 64]);
    gl_lds16(pb + i * 8 * 512, &Bs[0][(wave * 32 + i * 8) * 64]);
  }

  for (int it = 0; it < 8; it++) {
    const int buf = it & 1;
    __syncthreads();
    if (it < 7) {
      const int nb = buf ^ 1;
      const int ko = (it + 1) * 64;
#pragma unroll
      for (int i = 0; i < 4; i++) {
        gl_lds16(pa + ko + i * 8 * 512, &As[nb][(wave * 32 + i * 8) * 64]);
        gl_lds16(pb + ko + i * 8 * 512, &Bs[nb][(wave * 32 + i * 8) * 64]);
      }
    }
    bf16x8_t af[2][4], bfr[2][4];
#pragma unroll
    for (int i = 0; i < 4; i++) {
      const u16* ab = &As[buf][(wm * 64 + i * 16 + r) * 64];
      af[0][i] = *(const bf16x8_t*)(ab + ck0);
      af[1][i] = *(const bf16x8_t*)(ab + ck1);
    }
#pragma unroll
    for (int j = 0; j < 4; j++) {
      const u16* bb = &Bs[buf][(wn * 64 + j * 16 + r) * 64];
      bfr[0][j] = *(const bf16x8_t*)(bb + ck0);
      bfr[1][j] = *(const bf16x8_t*)(bb + ck1);
    }
#pragma unroll
    for (int kh = 0; kh < 2; kh++)
#pragma unroll
      for (int i = 0; i < 4; i++)
#pragma unroll
        for (int j = 0; j < 4; j++)
          acc[i][j] = mfma16(af[kh][i], bfr[kh][j], acc[i][j]);
  }

  float bv[4];
  if (MODE == 2) {
#pragma unroll
    for (int j = 0; j < 4; j++) bv[j] = bias[Nbase + wn * 64 + j * 16 + r];
  }
#pragma unroll
  for (int i = 0; i < 4; i++) {
#pragma unroll
    for (int reg = 0; reg < 4; reg++) {
      int gr = Mbase + wm * 64 + i * 16 + qd * 4 + reg;
#pragma unroll
      for (int j = 0; j < 4; j++) {
        int gc = Nbase + wn * 64 + j * 16 + r;
        float val = acc[i][j][reg];
        if (MODE == 2) {
          ((float*)Cout)[gr * 512 + gc] = val + bv[j];
        } else if (MODE == 1) {
          int bb = gc >> 12, ss = gc & 4095;
          ((__bf16*)Cout)[((long)(bb * 512 + gr)) * 4096 + ss] = (__bf16)val;
        } else {
          ((__bf16*)Cout)[gr * 512 + gc] = (__bf16)val;
        }
      }
    }
  }
}

__global__ __launch_bounds__(256) void gemm_qkv_kernel(
    const u16* __restrict__ X,
    const u16* __restrict__ Wq, const u16* __restrict__ Wk, const u16* __restrict__ Wv,
    u16* __restrict__ Q, u16* __restrict__ K, u16* __restrict__ Vt) {
  if (blockIdx.z == 0)
    gemm_core<0>(X, Wq, Q, nullptr, blockIdx.x * 128, blockIdx.y * 128);
  else if (blockIdx.z == 1)
    gemm_core<0>(X, Wk, K, nullptr, blockIdx.x * 128, blockIdx.y * 128);
  else
    gemm_core<1>(Wv, X, Vt, nullptr, blockIdx.y * 128, blockIdx.x * 128);
}

__global__ __launch_bounds__(256) void gemm_out_kernel(
    const u16* __restrict__ Aat, const u16* __restrict__ Wo,
    float* __restrict__ Out, const float* __restrict__ bo) {
  gemm_core<2>(Aat, Wo, Out, bo, blockIdx.x * 128, blockIdx.y * 128);
}

// ---------------- flash attention v6: register-direct P, MFMA row-sums ----------------
// grid (32, 16), block 256 (4 waves). Wave = (g = wave&1 -> 64-query group,
// kv = wave>>1 -> 2048-key half). QK^T transposed (A=K, B=Q) -> St C-layout ==
// B-layout of 16x16x16. PV swapped (O^T = V^T * P^T) from registers.
// L row-sums via A=ones 16x16x16 MFMA (no VALU adds, no epilogue shuffles).
__global__ __launch_bounds__(256, 2) void attn_kernel(
    const u16* __restrict__ Q, const u16* __restrict__ K, const u16* __restrict__ Vt,
    u16* __restrict__ Oattn) {
  __shared__ __align__(16) u16 Ks[2][2][4096];
  __shared__ __align__(16) u16 Vs[2][2][4096];

  const int t = threadIdx.x;
  const int wave = t >> 6, lane = t & 63;
  const int r = lane & 15, qd = lane >> 4;
  const int g = wave & 1, kv = wave >> 1;
  const int bh = blockIdx.y;
  const int b = bh >> 3, h = bh & 7;
  const long bbase = (long)b * 4096 * 512;
  const int q0 = blockIdx.x * 128;

  const int sw = r & 7;
  const int ck0 = (qd ^ sw) * 8;
  const int ck1 = ((qd + 4) ^ sw) * 8;
  int vck[4];
#pragma unroll
  for (int ks = 0; ks < 4; ks++)
    vck[ks] = ((ks * 2 + (qd >> 1)) ^ sw) * 8 + (qd & 1) * 4;

  s16x4 ones;
#pragma unroll
  for (int j = 0; j < 4; j++) ones[j] = (short)0x3F80;   // bf16 1.0

  // Q as B-operand fragments (resident)
  bf16x8_t qf[4][2];
#pragma unroll
  for (int qa = 0; qa < 4; qa++) {
    const u16* qp = Q + bbase + (long)(q0 + g * 64 + qa * 16 + r) * 512 + h * 64 + qd * 8;
    qf[qa][0] = *(const bf16x8_t*)(qp);
    qf[qa][1] = *(const bf16x8_t*)(qp + 32);
  }

  f32x4_t accO[4][4];   // [qa][dm]: O^T tile
  f32x4_t accL[4];      // [qa]: all regs equal = Σp over this wave's keys
#pragma unroll
  for (int qa = 0; qa < 4; qa++) {
    f32x4_t z = {0.f, 0.f, 0.f, 0.f};
    accL[qa] = z;
#pragma unroll
    for (int nt = 0; nt < 4; nt++) accO[qa][nt] = z;
  }

  const int rr = lane >> 3;
  const int cc = (lane & 7) ^ rr;
  const u16* kgb = K + bbase + (long)(kv * 2048 + g * 32 + rr) * 512 + h * 64 + cc * 8;
  const u16* vgb = Vt + ((long)(b * 512 + h * 64 + g * 32 + rr)) * 4096 + kv * 2048 + cc * 8;

  // prologue: tile 0 -> buf 0
#pragma unroll
  for (int i = 0; i < 4; i++) gl_lds16(kgb + (long)i * 8 * 512, &Ks[kv][0][g * 2048] + i * 512);
#pragma unroll
  for (int i = 0; i < 4; i++) gl_lds16(vgb + i * 8 * 4096, &Vs[kv][0][g * 2048] + i * 512);

  for (int it = 0; it < 32; it++) {
    const int buf = it & 1;
    __syncthreads();

    if (it < 31) {
      const int nb = (it + 1) & 1;
      const long ko = (long)(it + 1) * 64;
#pragma unroll
      for (int i = 0; i < 4; i++)
        gl_lds16(kgb + (ko + i * 8) * 512, &Ks[kv][nb][g * 2048] + i * 512);
#pragma unroll
      for (int i = 0; i < 4; i++)
        gl_lds16(vgb + ko + (long)i * 8 * 4096, &Vs[kv][nb][g * 2048] + i * 512);
    }

    // K as A-operand fragments
    bf16x8_t kf[4][2];
#pragma unroll
    for (int nt = 0; nt < 4; nt++) {
      const u16* kb = &Ks[kv][buf][(nt * 16 + r) * 64];
      kf[nt][0] = *(const bf16x8_t*)(kb + ck0);
      kf[nt][1] = *(const bf16x8_t*)(kb + ck1);
    }

    // transposed scores St[m=key][n=query]
    f32x4_t St[4][4];
#pragma unroll
    for (int qa = 0; qa < 4; qa++)
#pragma unroll
      for (int nt = 0; nt < 4; nt++) {
        f32x4_t z = {0.f, 0.f, 0.f, 0.f};
        z = mfma16(kf[nt][0], qf[qa][0], z);
        z = mfma16(kf[nt][1], qf[qa][1], z);
        St[qa][nt] = z;
      }

    // exp2 -> P in B-operand layout of 16x16x16 (packed cvt)
    s16x4 pk[4][4];
#pragma unroll
    for (int qa = 0; qa < 4; qa++)
#pragma unroll
      for (int nt = 0; nt < 4; nt++) {
        f32x4_t pe;
        pe[0] = __builtin_amdgcn_exp2f(St[qa][nt][0]);
        pe[1] = __builtin_amdgcn_exp2f(St[qa][nt][1]);
        pe[2] = __builtin_amdgcn_exp2f(St[qa][nt][2]);
        pe[3] = __builtin_amdgcn_exp2f(St[qa][nt][3]);
        bf16x4_t pb = __builtin_convertvector(pe, bf16x4_t);
        pk[qa][nt] = *(s16x4*)&pb;
      }

    // L row-sums via ones-MFMA (contracts across all 16 k -> all qd groups)
#pragma unroll
    for (int qa = 0; qa < 4; qa++)
#pragma unroll
      for (int ks = 0; ks < 4; ks++)
        accL[qa] = mfma16x16(ones, pk[qa][ks], accL[qa]);

    // PV swapped: accO^T[d][q] += V^T[d][k] * P^T[k][q]
#pragma unroll
    for (int ks = 0; ks < 4; ks++) {
      s16x4 va[4];
#pragma unroll
      for (int dm = 0; dm < 4; dm++)
        va[dm] = *(const s16x4*)&Vs[kv][buf][(dm * 16 + r) * 64 + vck[ks]];
#pragma unroll
      for (int qa = 0; qa < 4; qa++)
#pragma unroll
        for (int dm = 0; dm < 4; dm++)
          accO[qa][dm] = mfma16x16(va[dm], pk[qa][ks], accO[qa][dm]);
    }
  }

  // ---- combine split-K halves via LDS, normalize, store ----
  __syncthreads();
  float* Sc  = (float*)&Ks[0][0][0];   // 2 x 4096 f32 = 32 KB
  float* Lsc = (float*)&Vs[0][0][0];
  if (kv == 1) {
#pragma unroll
    for (int qa = 0; qa < 4; qa++) {
#pragma unroll
      for (int dm = 0; dm < 4; dm++)
        *(f32x4_t*)&Sc[g * 4096 + ((qa * 4 + dm) * 64 + lane) * 4] = accO[qa][dm];
      Lsc[g * 256 + qa * 64 + lane] = accL[qa][0];
    }
  }
  __syncthreads();
  if (kv == 0) {
#pragma unroll
    for (int qa = 0; qa < 4; qa++) {
      float L = accL[qa][0] + Lsc[g * 256 + qa * 64 + lane];
      float inv = 1.f / L;
      int gq = q0 + g * 64 + qa * 16 + r;
#pragma unroll
      for (int dm = 0; dm < 4; dm++) {
        f32x4_t o = *(const f32x4_t*)&Sc[g * 4096 + ((qa * 4 + dm) * 64 + lane) * 4];
        o += accO[qa][dm];
        bf16x4_t ob;
#pragma unroll
        for (int reg = 0; reg < 4; reg++) ob[reg] = (__bf16)(o[reg] * inv);
        *(uint2*)&Oattn[bbase + (long)gq * 512 + h * 64 + dm * 16 + qd * 4] = *(uint2*)&ob;
      }
    }
  }
}

// ---------------- launch ----------------
extern "C" void kernel_launch(void* const* d_in, const int* in_sizes, int n_in,
                              void* d_out, int out_size, void* d_ws, size_t ws_size,
                              hipStream_t stream) {
  const float* x  = (const float*)d_in[0];
  const float* Wq = (const float*)d_in[1];
  const float* Wk = (const float*)d_in[2];
  const float* Wv = (const float*)d_in[3];
  const float* Wo = (const float*)d_in[4];
  const float* bo = (const float*)d_in[5];
  float* out = (float*)d_out;

  u16* ws  = (u16*)d_ws;
  u16* xb  = ws;
  u16* wqb = xb  + 4194304;
  u16* wkb = wqb + 262144;
  u16* wvb = wkb + 262144;
  u16* wob = wvb + 262144;
  u16* Qb  = wob + 262144;
  u16* Kb  = Qb  + 4194304;
  u16* Vtg = Kb  + 4194304;   // V^T: [2*512][4096]
  u16* Ab  = Vtg + 4194304;

  cast_all_kernel<<<5120, 256, 0, stream>>>(x, Wq, Wk, Wv, Wo, xb, wqb, wkb, wvb, wob);

  dim3 g1(64, 4, 3);
  gemm_qkv_kernel<<<g1, 256, 0, stream>>>(xb, wqb, wkb, wvb, Qb, Kb, Vtg);

  dim3 g2(32, 16);
  attn_kernel<<<g2, 256, 0, stream>>>(Qb, Kb, Vtg, Ab);

  dim3 g3(64, 4);
  gemm_out_kernel<<<g3, 256, 0, stream>>>(Ab, wob, out, bo);
}

// Round 8
// 191.903 us; speedup vs baseline: 1.0941x; 1.0941x over previous
//
#include <hip/hip_runtime.h>

// Problem constants: B=2, S=4096, H=8, DH=64, D=512, M = B*S = 8192.
#define LOG2E 1.44269504088896340736f

typedef unsigned short u16;
typedef __bf16 bf16x4_t __attribute__((ext_vector_type(4)));
typedef __bf16 bf16x8_t __attribute__((ext_vector_type(8)));
typedef float f32x4_t __attribute__((ext_vector_type(4)));

__device__ __forceinline__ u16 f2bf(float f) {
  union { float f; unsigned int u; } v;
  v.f = f;
  unsigned int u = v.u;
  u += 0x7fffu + ((u >> 16) & 1u);
  return (u16)(u >> 16);
}

__device__ __forceinline__ f32x4_t mfma16(bf16x8_t a, bf16x8_t b, f32x4_t c) {
  return __builtin_amdgcn_mfma_f32_16x16x32_bf16(a, b, c, 0, 0, 0);
}

// async 16B global -> LDS (dest = wave-uniform base + lane*16)
__device__ __forceinline__ void gl_lds16(const u16* g, u16* l) {
  __builtin_amdgcn_global_load_lds(
      (const __attribute__((address_space(1))) unsigned int*)g,
      (__attribute__((address_space(3))) unsigned int*)l, 16, 0, 0);
}

// ---------------- cast fp32 -> bf16 (Wq pre-scaled by 0.125*log2e) ----------------
__global__ __launch_bounds__(256) void cast_all_kernel(
    const float* __restrict__ x, const float* __restrict__ wq, const float* __restrict__ wk,
    const float* __restrict__ wv, const float* __restrict__ wo,
    u16* __restrict__ xb, u16* __restrict__ wqb, u16* __restrict__ wkb,
    u16* __restrict__ wvb, u16* __restrict__ wob) {
  const int NX = 2 * 4096 * 512;
  const int NW = 512 * 512;
  int i = (blockIdx.x * 256 + threadIdx.x) * 4;
  const float* src; u16* dst; int off; float scale = 1.f;
  if (i < NX)               { src = x;  dst = xb;  off = i; }
  else if (i < NX + NW)     { src = wq; dst = wqb; off = i - NX; scale = 0.125f * LOG2E; }
  else if (i < NX + 2 * NW) { src = wk; dst = wkb; off = i - NX - NW; }
  else if (i < NX + 3 * NW) { src = wv; dst = wvb; off = i - NX - 2 * NW; }
  else                      { src = wo; dst = wob; off = i - NX - 3 * NW; }
  float4 f = *(const float4*)(src + off);
  unsigned int lo = (unsigned int)f2bf(f.x * scale) | ((unsigned int)f2bf(f.y * scale) << 16);
  unsigned int hi = (unsigned int)f2bf(f.z * scale) | ((unsigned int)f2bf(f.w * scale) << 16);
  uint2 o; o.x = lo; o.y = hi;
  *(uint2*)(dst + off) = o;
}

// ---------------- GEMM: C[M,N] = A[M,512] @ Bt[N,512]^T (both bf16, K-contig) ----------------
// R6 version (register-prefetch, BK=32): proven fastest aggregate so far.
// MODE 0: bf16 row-major C. MODE 1: V^T store. MODE 2: fp32 + bias.
template <int MODE>
__device__ __forceinline__ void gemm_core(const u16* __restrict__ A, const u16* __restrict__ Bt,
                                          void* __restrict__ Cout, const float* __restrict__ bias,
                                          int Mbase, int Nbase) {
  __shared__ __align__(16) u16 As[128][40];
  __shared__ __align__(16) u16 Bs[128][40];
  const int t = threadIdx.x;
  const int wave = t >> 6, lane = t & 63;
  const int r = lane & 15, qd = lane >> 4;
  const int wm = wave & 1, wn = wave >> 1;
  const int lr = t >> 2;
  const int lc = (t & 3) * 8;

  f32x4_t acc[4][4];
#pragma unroll
  for (int i = 0; i < 4; i++)
#pragma unroll
    for (int j = 0; j < 4; j++) { f32x4_t z = {0.f, 0.f, 0.f, 0.f}; acc[i][j] = z; }

  const u16* pa0 = A  + (Mbase + lr) * 512 + lc;
  const u16* pa1 = A  + (Mbase + 64 + lr) * 512 + lc;
  const u16* pb0 = Bt + (Nbase + lr) * 512 + lc;
  const u16* pb1 = Bt + (Nbase + 64 + lr) * 512 + lc;

  uint4 ra0 = *(const uint4*)(pa0);
  uint4 ra1 = *(const uint4*)(pa1);
  uint4 rb0 = *(const uint4*)(pb0);
  uint4 rb1 = *(const uint4*)(pb1);

  for (int k0 = 0; k0 < 512; k0 += 32) {
    *(uint4*)&As[lr][lc]      = ra0;
    *(uint4*)&As[64 + lr][lc] = ra1;
    *(uint4*)&Bs[lr][lc]      = rb0;
    *(uint4*)&Bs[64 + lr][lc] = rb1;
    __syncthreads();
    if (k0 < 480) {
      ra0 = *(const uint4*)(pa0 + k0 + 32);
      ra1 = *(const uint4*)(pa1 + k0 + 32);
      rb0 = *(const uint4*)(pb0 + k0 + 32);
      rb1 = *(const uint4*)(pb1 + k0 + 32);
    }
    bf16x8_t af[4], bfr[4];
#pragma unroll
    for (int i = 0; i < 4; i++) af[i]  = *(const bf16x8_t*)&As[wm * 64 + i * 16 + r][qd * 8];
#pragma unroll
    for (int j = 0; j < 4; j++) bfr[j] = *(const bf16x8_t*)&Bs[wn * 64 + j * 16 + r][qd * 8];
#pragma unroll
    for (int i = 0; i < 4; i++)
#pragma unroll
      for (int j = 0; j < 4; j++) acc[i][j] = mfma16(af[i], bfr[j], acc[i][j]);
    __syncthreads();
  }

  float bv[4];
  if (MODE == 2) {
#pragma unroll
    for (int j = 0; j < 4; j++) bv[j] = bias[Nbase + wn * 64 + j * 16 + r];
  }
#pragma unroll
  for (int i = 0; i < 4; i++) {
#pragma unroll
    for (int reg = 0; reg < 4; reg++) {
      int gr = Mbase + wm * 64 + i * 16 + qd * 4 + reg;
#pragma unroll
      for (int j = 0; j < 4; j++) {
        int gc = Nbase + wn * 64 + j * 16 + r;
        float val = acc[i][j][reg];
        if (MODE == 2) {
          ((float*)Cout)[gr * 512 + gc] = val + bv[j];
        } else if (MODE == 1) {
          int bb = gc >> 12, ss = gc & 4095;
          ((__bf16*)Cout)[((long)(bb * 512 + gr)) * 4096 + ss] = (__bf16)val;
        } else {
          ((__bf16*)Cout)[gr * 512 + gc] = (__bf16)val;
        }
      }
    }
  }
}

__global__ __launch_bounds__(256) void gemm_qkv_kernel(
    const u16* __restrict__ X,
    const u16* __restrict__ Wq, const u16* __restrict__ Wk, const u16* __restrict__ Wv,
    u16* __restrict__ Q, u16* __restrict__ K, u16* __restrict__ Vt) {
  if (blockIdx.z == 0)
    gemm_core<0>(X, Wq, Q, nullptr, blockIdx.x * 128, blockIdx.y * 128);
  else if (blockIdx.z == 1)
    gemm_core<0>(X, Wk, K, nullptr, blockIdx.x * 128, blockIdx.y * 128);
  else
    gemm_core<1>(Wv, X, Vt, nullptr, blockIdx.y * 128, blockIdx.x * 128);
}

__global__ __launch_bounds__(256) void gemm_out_kernel(
    const u16* __restrict__ Aat, const u16* __restrict__ Wo,
    float* __restrict__ Out, const float* __restrict__ bo) {
  gemm_core<2>(Aat, Wo, Out, bo, blockIdx.x * 128, blockIdx.y * 128);
}

// ---------------- flash attention v7: full-K PV via key relabeling ----------------
// grid (32, 16), block 256 (4 waves). Wave = (g = wave&1 -> 64-query group,
// kv = wave>>1 -> 2048-key half). QK^T transposed (A=K, B=Q): St C-layout gives
// lane (qd,r) keys {4qd..4qd+3} of each 16-key tile. PV uses 16x16x32 with
// k-slot relabeling phi(qd*8+j) = c*32 + 4qd + j (j<4) / c*32+16+4qd+j-4 (j>=4):
// P B-frag = concat of two St quads' exp (register-only), V A-frag = two b64
// LDS reads. All MFMAs full-rate 16x16x32 (16x16x16 measured ~17.4cyc = full cost).
__global__ __launch_bounds__(256, 2) void attn_kernel(
    const u16* __restrict__ Q, const u16* __restrict__ K, const u16* __restrict__ Vt,
    u16* __restrict__ Oattn) {
  __shared__ __align__(16) u16 Ks[2][2][4096];
  __shared__ __align__(16) u16 Vs[2][2][4096];

  const int t = threadIdx.x;
  const int wave = t >> 6, lane = t & 63;
  const int r = lane & 15, qd = lane >> 4;
  const int g = wave & 1, kv = wave >> 1;
  const int bh = blockIdx.y;
  const int b = bh >> 3, h = bh & 7;
  const long bbase = (long)b * 4096 * 512;
  const int q0 = blockIdx.x * 128;

  const int sw = r & 7;
  const int ck0 = (qd ^ sw) * 8;
  const int ck1 = ((qd + 4) ^ sw) * 8;
  // V A-frag b64 slot offsets per 32-key chunk c: keys c*32+4qd and c*32+16+4qd
  int vo0[2], vo1[2];
#pragma unroll
  for (int c = 0; c < 2; c++) {
    vo0[c] = ((c * 4 + (qd >> 1)) ^ sw) * 8 + 4 * (qd & 1);
    vo1[c] = ((c * 4 + 2 + (qd >> 1)) ^ sw) * 8 + 4 * (qd & 1);
  }

  bf16x8_t ones8;
#pragma unroll
  for (int j = 0; j < 8; j++) ones8[j] = (__bf16)1.0f;

  // Q as B-operand fragments (resident)
  bf16x8_t qf[4][2];
#pragma unroll
  for (int qa = 0; qa < 4; qa++) {
    const u16* qp = Q + bbase + (long)(q0 + g * 64 + qa * 16 + r) * 512 + h * 64 + qd * 8;
    qf[qa][0] = *(const bf16x8_t*)(qp);
    qf[qa][1] = *(const bf16x8_t*)(qp + 32);
  }

  f32x4_t accO[4][4];   // [qa][dm]: O^T tile (col=query=r, row=d=qd*4+reg)
  f32x4_t accL[4];      // [qa]: every reg = Sigma p over this wave's keys
#pragma unroll
  for (int qa = 0; qa < 4; qa++) {
    f32x4_t z = {0.f, 0.f, 0.f, 0.f};
    accL[qa] = z;
#pragma unroll
    for (int nt = 0; nt < 4; nt++) accO[qa][nt] = z;
  }

  const int rr = lane >> 3;
  const int cc = (lane & 7) ^ rr;
  const u16* kgb = K + bbase + (long)(kv * 2048 + g * 32 + rr) * 512 + h * 64 + cc * 8;
  const u16* vgb = Vt + ((long)(b * 512 + h * 64 + g * 32 + rr)) * 4096 + kv * 2048 + cc * 8;

  // prologue: tile 0 -> buf 0
#pragma unroll
  for (int i = 0; i < 4; i++) gl_lds16(kgb + (long)i * 8 * 512, &Ks[kv][0][g * 2048] + i * 512);
#pragma unroll
  for (int i = 0; i < 4; i++) gl_lds16(vgb + i * 8 * 4096, &Vs[kv][0][g * 2048] + i * 512);

  for (int it = 0; it < 32; it++) {
    const int buf = it & 1;
    __syncthreads();

    if (it < 31) {
      const int nb = (it + 1) & 1;
      const long ko = (long)(it + 1) * 64;
#pragma unroll
      for (int i = 0; i < 4; i++)
        gl_lds16(kgb + (ko + i * 8) * 512, &Ks[kv][nb][g * 2048] + i * 512);
#pragma unroll
      for (int i = 0; i < 4; i++)
        gl_lds16(vgb + ko + (long)i * 8 * 4096, &Vs[kv][nb][g * 2048] + i * 512);
    }

    // K as A-operand fragments
    bf16x8_t kf[4][2];
#pragma unroll
    for (int nt = 0; nt < 4; nt++) {
      const u16* kb = &Ks[kv][buf][(nt * 16 + r) * 64];
      kf[nt][0] = *(const bf16x8_t*)(kb + ck0);
      kf[nt][1] = *(const bf16x8_t*)(kb + ck1);
    }

    // transposed scores St[m=key][n=query]
    f32x4_t St[4][4];
#pragma unroll
    for (int qa = 0; qa < 4; qa++)
#pragma unroll
      for (int nt = 0; nt < 4; nt++) {
        f32x4_t z = {0.f, 0.f, 0.f, 0.f};
        z = mfma16(kf[nt][0], qf[qa][0], z);
        z = mfma16(kf[nt][1], qf[qa][1], z);
        St[qa][nt] = z;
      }

    // exp2 -> P directly as 16x16x32 B-fragments: pf[qa][c] slots j=0..7 =
    // [tile 2c regs 0-3, tile 2c+1 regs 0-3]  (register concat, no movement)
    bf16x8_t pf[4][2];
#pragma unroll
    for (int qa = 0; qa < 4; qa++)
#pragma unroll
      for (int c = 0; c < 2; c++) {
        f32x4_t e0, e1;
#pragma unroll
        for (int j = 0; j < 4; j++) {
          e0[j] = __builtin_amdgcn_exp2f(St[qa][2 * c][j]);
          e1[j] = __builtin_amdgcn_exp2f(St[qa][2 * c + 1][j]);
        }
        bf16x4_t b0 = __builtin_convertvector(e0, bf16x4_t);
        bf16x4_t b1 = __builtin_convertvector(e1, bf16x4_t);
        bf16x8_t p8;
#pragma unroll
        for (int j = 0; j < 4; j++) { p8[j] = b0[j]; p8[4 + j] = b1[j]; }
        pf[qa][c] = p8;
      }

    // L row-sums via ones-MFMA (full-K)
#pragma unroll
    for (int qa = 0; qa < 4; qa++)
#pragma unroll
      for (int c = 0; c < 2; c++)
        accL[qa] = mfma16(ones8, pf[qa][c], accL[qa]);

    // PV: accO^T[d][q] += V^T[d][phi(k)] * P^T[phi(k)][q], 32 keys per chunk
#pragma unroll
    for (int c = 0; c < 2; c++) {
      bf16x8_t va[4];
#pragma unroll
      for (int dm = 0; dm < 4; dm++) {
        const u16* vb = &Vs[kv][buf][(dm * 16 + r) * 64];
        union { uint4 u; bf16x8_t v; } cat;
        *(uint2*)&cat.u.x = *(const uint2*)(vb + vo0[c]);
        *(uint2*)&cat.u.z = *(const uint2*)(vb + vo1[c]);
        va[dm] = cat.v;
      }
#pragma unroll
      for (int qa = 0; qa < 4; qa++)
#pragma unroll
        for (int dm = 0; dm < 4; dm++)
          accO[qa][dm] = mfma16(va[dm], pf[qa][c], accO[qa][dm]);
    }
  }

  // ---- combine split-K halves via LDS, normalize, store ----
  __syncthreads();
  float* Sc  = (float*)&Ks[0][0][0];   // 2 x 4096 f32 = 32 KB
  float* Lsc = (float*)&Vs[0][0][0];
  if (kv == 1) {
#pragma unroll
    for (int qa = 0; qa < 4; qa++) {
#pragma unroll
      for (int dm = 0; dm < 4; dm++)
        *(f32x4_t*)&Sc[g * 4096 + ((qa * 4 + dm) * 64 + lane) * 4] = accO[qa][dm];
      Lsc[g * 256 + qa * 64 + lane] = accL[qa][0];
    }
  }
  __syncthreads();
  if (kv == 0) {
#pragma unroll
    for (int qa = 0; qa < 4; qa++) {
      float L = accL[qa][0] + Lsc[g * 256 + qa * 64 + lane];
      float inv = 1.f / L;
      int gq = q0 + g * 64 + qa * 16 + r;
#pragma unroll
      for (int dm = 0; dm < 4; dm++) {
        f32x4_t o = *(const f32x4_t*)&Sc[g * 4096 + ((qa * 4 + dm) * 64 + lane) * 4];
        o += accO[qa][dm];
        bf16x4_t ob;
#pragma unroll
        for (int reg = 0; reg < 4; reg++) ob[reg] = (__bf16)(o[reg] * inv);
        *(uint2*)&Oattn[bbase + (long)gq * 512 + h * 64 + dm * 16 + qd * 4] = *(uint2*)&ob;
      }
    }
  }
}

// ---------------- launch ----------------
extern "C" void kernel_launch(void* const* d_in, const int* in_sizes, int n_in,
                              void* d_out, int out_size, void* d_ws, size_t ws_size,
                              hipStream_t stream) {
  const float* x  = (const float*)d_in[0];
  const float* Wq = (const float*)d_in[1];
  const float* Wk = (const float*)d_in[2];
  const float* Wv = (const float*)d_in[3];
  const float* Wo = (const float*)d_in[4];
  const float* bo = (const float*)d_in[5];
  float* out = (float*)d_out;

  u16* ws  = (u16*)d_ws;
  u16* xb  = ws;
  u16* wqb = xb  + 4194304;
  u16* wkb = wqb + 262144;
  u16* wvb = wkb + 262144;
  u16* wob = wvb + 262144;
  u16* Qb  = wob + 262144;
  u16* Kb  = Qb  + 4194304;
  u16* Vtg = Kb  + 4194304;   // V^T: [2*512][4096]
  u16* Ab  = Vtg + 4194304;

  cast_all_kernel<<<5120, 256, 0, stream>>>(x, Wq, Wk, Wv, Wo, xb, wqb, wkb, wvb, wob);

  dim3 g1(64, 4, 3);
  gemm_qkv_kernel<<<g1, 256, 0, stream>>>(xb, wqb, wkb, wvb, Qb, Kb, Vtg);

  dim3 g2(32, 16);
  attn_kernel<<<g2, 256, 0, stream>>>(Qb, Kb, Vtg, Ab);

  dim3 g3(64, 4);
  gemm_out_kernel<<<g3, 256, 0, stream>>>(Ab, wob, out, bo);
}

// Round 9
// 187.667 us; speedup vs baseline: 1.1188x; 1.0226x over previous
//
#include <hip/hip_runtime.h>

// Problem constants: B=2, S=4096, H=8, DH=64, D=512, M = B*S = 8192.
#define LOG2E 1.44269504088896340736f

typedef unsigned short u16;
typedef __bf16 bf16x4_t __attribute__((ext_vector_type(4)));
typedef __bf16 bf16x8_t __attribute__((ext_vector_type(8)));
typedef float f32x4_t __attribute__((ext_vector_type(4)));

__device__ __forceinline__ f32x4_t mfma16(bf16x8_t a, bf16x8_t b, f32x4_t c) {
  return __builtin_amdgcn_mfma_f32_16x16x32_bf16(a, b, c, 0, 0, 0);
}

// async 16B global -> LDS (dest = wave-uniform base + lane*16)
__device__ __forceinline__ void gl_lds16(const u16* g, u16* l) {
  __builtin_amdgcn_global_load_lds(
      (const __attribute__((address_space(1))) unsigned int*)g,
      (__attribute__((address_space(3))) unsigned int*)l, 16, 0, 0);
}

// convert 8 fp32 (two f32x4) -> 8 bf16, scaled, store 16B to LDS
__device__ __forceinline__ void cvt_store(u16* dst, f32x4_t a, f32x4_t b, float scale) {
  a *= scale; b *= scale;
  union { uint4 u; struct { bf16x4_t lo, hi; } s; } c;
  c.s.lo = __builtin_convertvector(a, bf16x4_t);
  c.s.hi = __builtin_convertvector(b, bf16x4_t);
  *(uint4*)dst = c.u;
}

// ---------------- GEMM (fp32 inputs, fused cast): C = A[M,512] @ Bt[N,512]^T ----------------
// MODE 0: bf16 row-major C (stride 512). MODE 1: V^T scatter store.
// Register-prefetch pipeline (BK=32), fp32->bf16 convert at LDS-write time.
template <int MODE>
__device__ __forceinline__ void gemm_core_f32(const float* __restrict__ A, const float* __restrict__ Bt,
                                              u16* __restrict__ Cout, int Mbase, int Nbase,
                                              float bscale) {
  __shared__ __align__(16) u16 As[128][40];
  __shared__ __align__(16) u16 Bs[128][40];
  const int t = threadIdx.x;
  const int wave = t >> 6, lane = t & 63;
  const int r = lane & 15, qd = lane >> 4;
  const int wm = wave & 1, wn = wave >> 1;
  const int lr = t >> 2;
  const int lc = (t & 3) * 8;

  f32x4_t acc[4][4];
#pragma unroll
  for (int i = 0; i < 4; i++)
#pragma unroll
    for (int j = 0; j < 4; j++) { f32x4_t z = {0.f, 0.f, 0.f, 0.f}; acc[i][j] = z; }

  const float* pa0 = A  + (Mbase + lr) * 512 + lc;
  const float* pa1 = A  + (Mbase + 64 + lr) * 512 + lc;
  const float* pb0 = Bt + (Nbase + lr) * 512 + lc;
  const float* pb1 = Bt + (Nbase + 64 + lr) * 512 + lc;

  f32x4_t ra0[2], ra1[2], rb0[2], rb1[2];
  ra0[0] = *(const f32x4_t*)(pa0); ra0[1] = *(const f32x4_t*)(pa0 + 4);
  ra1[0] = *(const f32x4_t*)(pa1); ra1[1] = *(const f32x4_t*)(pa1 + 4);
  rb0[0] = *(const f32x4_t*)(pb0); rb0[1] = *(const f32x4_t*)(pb0 + 4);
  rb1[0] = *(const f32x4_t*)(pb1); rb1[1] = *(const f32x4_t*)(pb1 + 4);

  for (int k0 = 0; k0 < 512; k0 += 32) {
    cvt_store(&As[lr][lc],      ra0[0], ra0[1], 1.f);
    cvt_store(&As[64 + lr][lc], ra1[0], ra1[1], 1.f);
    cvt_store(&Bs[lr][lc],      rb0[0], rb0[1], bscale);
    cvt_store(&Bs[64 + lr][lc], rb1[0], rb1[1], bscale);
    __syncthreads();
    if (k0 < 480) {
      ra0[0] = *(const f32x4_t*)(pa0 + k0 + 32); ra0[1] = *(const f32x4_t*)(pa0 + k0 + 36);
      ra1[0] = *(const f32x4_t*)(pa1 + k0 + 32); ra1[1] = *(const f32x4_t*)(pa1 + k0 + 36);
      rb0[0] = *(const f32x4_t*)(pb0 + k0 + 32); rb0[1] = *(const f32x4_t*)(pb0 + k0 + 36);
      rb1[0] = *(const f32x4_t*)(pb1 + k0 + 32); rb1[1] = *(const f32x4_t*)(pb1 + k0 + 36);
    }
    bf16x8_t af[4], bfr[4];
#pragma unroll
    for (int i = 0; i < 4; i++) af[i]  = *(const bf16x8_t*)&As[wm * 64 + i * 16 + r][qd * 8];
#pragma unroll
    for (int j = 0; j < 4; j++) bfr[j] = *(const bf16x8_t*)&Bs[wn * 64 + j * 16 + r][qd * 8];
#pragma unroll
    for (int i = 0; i < 4; i++)
#pragma unroll
      for (int j = 0; j < 4; j++) acc[i][j] = mfma16(af[i], bfr[j], acc[i][j]);
    __syncthreads();
  }

#pragma unroll
  for (int i = 0; i < 4; i++) {
#pragma unroll
    for (int reg = 0; reg < 4; reg++) {
      int gr = Mbase + wm * 64 + i * 16 + qd * 4 + reg;
#pragma unroll
      for (int j = 0; j < 4; j++) {
        int gc = Nbase + wn * 64 + j * 16 + r;
        float val = acc[i][j][reg];
        if (MODE == 1) {
          int bb = gc >> 12, ss = gc & 4095;
          ((__bf16*)Cout)[((long)(bb * 512 + gr)) * 4096 + ss] = (__bf16)val;
        } else {
          ((__bf16*)Cout)[gr * 512 + gc] = (__bf16)val;
        }
      }
    }
  }
}

__global__ __launch_bounds__(256) void gemm_qkv_kernel(
    const float* __restrict__ X,
    const float* __restrict__ Wq, const float* __restrict__ Wk, const float* __restrict__ Wv,
    u16* __restrict__ Q, u16* __restrict__ K, u16* __restrict__ Vt) {
  if (blockIdx.z == 0)
    gemm_core_f32<0>(X, Wq, Q, blockIdx.x * 128, blockIdx.y * 128, 0.125f * LOG2E);
  else if (blockIdx.z == 1)
    gemm_core_f32<0>(X, Wk, K, blockIdx.x * 128, blockIdx.y * 128, 1.f);
  else  // V^T = Wv @ X^T
    gemm_core_f32<1>(Wv, X, Vt, blockIdx.y * 128, blockIdx.x * 128, 1.f);
}

// ---------------- out-proj GEMM: Out[M,512] = Ab[M,512](bf16) @ Wo[512,512]^T(f32) + bo ----
// 64x128 tile, grid (128,4) = 512 blocks -> 2 blocks/CU. 4 waves split N (32 each).
__global__ __launch_bounds__(256) void gemm_out_kernel(
    const u16* __restrict__ Aat, const float* __restrict__ Wo,
    float* __restrict__ Out, const float* __restrict__ bo) {
  __shared__ __align__(16) u16 As[64][40];
  __shared__ __align__(16) u16 Bs[128][40];
  const int t = threadIdx.x;
  const int wave = t >> 6, lane = t & 63;
  const int r = lane & 15, qd = lane >> 4;
  const int wn = wave;
  const int Mbase = blockIdx.x * 64, Nbase = blockIdx.y * 128;
  const int lr = t >> 2;
  const int lc = (t & 3) * 8;

  f32x4_t acc[4][2];
#pragma unroll
  for (int i = 0; i < 4; i++)
#pragma unroll
    for (int j = 0; j < 2; j++) { f32x4_t z = {0.f, 0.f, 0.f, 0.f}; acc[i][j] = z; }

  const u16*  pa  = Aat + (Mbase + lr) * 512 + lc;
  const float* pb0 = Wo + (Nbase + lr) * 512 + lc;
  const float* pb1 = Wo + (Nbase + 64 + lr) * 512 + lc;

  uint4 ra = *(const uint4*)(pa);
  f32x4_t rb0[2], rb1[2];
  rb0[0] = *(const f32x4_t*)(pb0); rb0[1] = *(const f32x4_t*)(pb0 + 4);
  rb1[0] = *(const f32x4_t*)(pb1); rb1[1] = *(const f32x4_t*)(pb1 + 4);

  for (int k0 = 0; k0 < 512; k0 += 32) {
    *(uint4*)&As[lr][lc] = ra;
    cvt_store(&Bs[lr][lc],      rb0[0], rb0[1], 1.f);
    cvt_store(&Bs[64 + lr][lc], rb1[0], rb1[1], 1.f);
    __syncthreads();
    if (k0 < 480) {
      ra = *(const uint4*)(pa + k0 + 32);
      rb0[0] = *(const f32x4_t*)(pb0 + k0 + 32); rb0[1] = *(const f32x4_t*)(pb0 + k0 + 36);
      rb1[0] = *(const f32x4_t*)(pb1 + k0 + 32); rb1[1] = *(const f32x4_t*)(pb1 + k0 + 36);
    }
    bf16x8_t af[4], bfr[2];
#pragma unroll
    for (int i = 0; i < 4; i++) af[i]  = *(const bf16x8_t*)&As[i * 16 + r][qd * 8];
#pragma unroll
    for (int j = 0; j < 2; j++) bfr[j] = *(const bf16x8_t*)&Bs[wn * 32 + j * 16 + r][qd * 8];
#pragma unroll
    for (int i = 0; i < 4; i++)
#pragma unroll
      for (int j = 0; j < 2; j++) acc[i][j] = mfma16(af[i], bfr[j], acc[i][j]);
    __syncthreads();
  }

  float bv[2];
#pragma unroll
  for (int j = 0; j < 2; j++) bv[j] = bo[Nbase + wn * 32 + j * 16 + r];
#pragma unroll
  for (int i = 0; i < 4; i++)
#pragma unroll
    for (int reg = 0; reg < 4; reg++) {
      int gr = Mbase + i * 16 + qd * 4 + reg;
#pragma unroll
      for (int j = 0; j < 2; j++) {
        int gc = Nbase + wn * 32 + j * 16 + r;
        Out[gr * 512 + gc] = acc[i][j][reg] + bv[j];
      }
    }
}

// ---------------- flash attention v7 (unchanged from R8): full-K PV via key relabeling ----
__global__ __launch_bounds__(256, 2) void attn_kernel(
    const u16* __restrict__ Q, const u16* __restrict__ K, const u16* __restrict__ Vt,
    u16* __restrict__ Oattn) {
  __shared__ __align__(16) u16 Ks[2][2][4096];
  __shared__ __align__(16) u16 Vs[2][2][4096];

  const int t = threadIdx.x;
  const int wave = t >> 6, lane = t & 63;
  const int r = lane & 15, qd = lane >> 4;
  const int g = wave & 1, kv = wave >> 1;
  const int bh = blockIdx.y;
  const int b = bh >> 3, h = bh & 7;
  const long bbase = (long)b * 4096 * 512;
  const int q0 = blockIdx.x * 128;

  const int sw = r & 7;
  const int ck0 = (qd ^ sw) * 8;
  const int ck1 = ((qd + 4) ^ sw) * 8;
  int vo0[2], vo1[2];
#pragma unroll
  for (int c = 0; c < 2; c++) {
    vo0[c] = ((c * 4 + (qd >> 1)) ^ sw) * 8 + 4 * (qd & 1);
    vo1[c] = ((c * 4 + 2 + (qd >> 1)) ^ sw) * 8 + 4 * (qd & 1);
  }

  bf16x8_t ones8;
#pragma unroll
  for (int j = 0; j < 8; j++) ones8[j] = (__bf16)1.0f;

  bf16x8_t qf[4][2];
#pragma unroll
  for (int qa = 0; qa < 4; qa++) {
    const u16* qp = Q + bbase + (long)(q0 + g * 64 + qa * 16 + r) * 512 + h * 64 + qd * 8;
    qf[qa][0] = *(const bf16x8_t*)(qp);
    qf[qa][1] = *(const bf16x8_t*)(qp + 32);
  }

  f32x4_t accO[4][4];
  f32x4_t accL[4];
#pragma unroll
  for (int qa = 0; qa < 4; qa++) {
    f32x4_t z = {0.f, 0.f, 0.f, 0.f};
    accL[qa] = z;
#pragma unroll
    for (int nt = 0; nt < 4; nt++) accO[qa][nt] = z;
  }

  const int rr = lane >> 3;
  const int cc = (lane & 7) ^ rr;
  const u16* kgb = K + bbase + (long)(kv * 2048 + g * 32 + rr) * 512 + h * 64 + cc * 8;
  const u16* vgb = Vt + ((long)(b * 512 + h * 64 + g * 32 + rr)) * 4096 + kv * 2048 + cc * 8;

#pragma unroll
  for (int i = 0; i < 4; i++) gl_lds16(kgb + (long)i * 8 * 512, &Ks[kv][0][g * 2048] + i * 512);
#pragma unroll
  for (int i = 0; i < 4; i++) gl_lds16(vgb + i * 8 * 4096, &Vs[kv][0][g * 2048] + i * 512);

  for (int it = 0; it < 32; it++) {
    const int buf = it & 1;
    __syncthreads();

    if (it < 31) {
      const int nb = (it + 1) & 1;
      const long ko = (long)(it + 1) * 64;
#pragma unroll
      for (int i = 0; i < 4; i++)
        gl_lds16(kgb + (ko + i * 8) * 512, &Ks[kv][nb][g * 2048] + i * 512);
#pragma unroll
      for (int i = 0; i < 4; i++)
        gl_lds16(vgb + ko + (long)i * 8 * 4096, &Vs[kv][nb][g * 2048] + i * 512);
    }

    bf16x8_t kf[4][2];
#pragma unroll
    for (int nt = 0; nt < 4; nt++) {
      const u16* kb = &Ks[kv][buf][(nt * 16 + r) * 64];
      kf[nt][0] = *(const bf16x8_t*)(kb + ck0);
      kf[nt][1] = *(const bf16x8_t*)(kb + ck1);
    }

    f32x4_t St[4][4];
#pragma unroll
    for (int qa = 0; qa < 4; qa++)
#pragma unroll
      for (int nt = 0; nt < 4; nt++) {
        f32x4_t z = {0.f, 0.f, 0.f, 0.f};
        z = mfma16(kf[nt][0], qf[qa][0], z);
        z = mfma16(kf[nt][1], qf[qa][1], z);
        St[qa][nt] = z;
      }

    bf16x8_t pf[4][2];
#pragma unroll
    for (int qa = 0; qa < 4; qa++)
#pragma unroll
      for (int c = 0; c < 2; c++) {
        f32x4_t e0, e1;
#pragma unroll
        for (int j = 0; j < 4; j++) {
          e0[j] = __builtin_amdgcn_exp2f(St[qa][2 * c][j]);
          e1[j] = __builtin_amdgcn_exp2f(St[qa][2 * c + 1][j]);
        }
        bf16x4_t b0 = __builtin_convertvector(e0, bf16x4_t);
        bf16x4_t b1 = __builtin_convertvector(e1, bf16x4_t);
        bf16x8_t p8;
#pragma unroll
        for (int j = 0; j < 4; j++) { p8[j] = b0[j]; p8[4 + j] = b1[j]; }
        pf[qa][c] = p8;
      }

#pragma unroll
    for (int qa = 0; qa < 4; qa++)
#pragma unroll
      for (int c = 0; c < 2; c++)
        accL[qa] = mfma16(ones8, pf[qa][c], accL[qa]);

#pragma unroll
    for (int c = 0; c < 2; c++) {
      bf16x8_t va[4];
#pragma unroll
      for (int dm = 0; dm < 4; dm++) {
        const u16* vb = &Vs[kv][buf][(dm * 16 + r) * 64];
        union { uint4 u; bf16x8_t v; } cat;
        *(uint2*)&cat.u.x = *(const uint2*)(vb + vo0[c]);
        *(uint2*)&cat.u.z = *(const uint2*)(vb + vo1[c]);
        va[dm] = cat.v;
      }
#pragma unroll
      for (int qa = 0; qa < 4; qa++)
#pragma unroll
        for (int dm = 0; dm < 4; dm++)
          accO[qa][dm] = mfma16(va[dm], pf[qa][c], accO[qa][dm]);
    }
  }

  __syncthreads();
  float* Sc  = (float*)&Ks[0][0][0];
  float* Lsc = (float*)&Vs[0][0][0];
  if (kv == 1) {
#pragma unroll
    for (int qa = 0; qa < 4; qa++) {
#pragma unroll
      for (int dm = 0; dm < 4; dm++)
        *(f32x4_t*)&Sc[g * 4096 + ((qa * 4 + dm) * 64 + lane) * 4] = accO[qa][dm];
      Lsc[g * 256 + qa * 64 + lane] = accL[qa][0];
    }
  }
  __syncthreads();
  if (kv == 0) {
#pragma unroll
    for (int qa = 0; qa < 4; qa++) {
      float L = accL[qa][0] + Lsc[g * 256 + qa * 64 + lane];
      float inv = 1.f / L;
      int gq = q0 + g * 64 + qa * 16 + r;
#pragma unroll
      for (int dm = 0; dm < 4; dm++) {
        f32x4_t o = *(const f32x4_t*)&Sc[g * 4096 + ((qa * 4 + dm) * 64 + lane) * 4];
        o += accO[qa][dm];
        bf16x4_t ob;
#pragma unroll
        for (int reg = 0; reg < 4; reg++) ob[reg] = (__bf16)(o[reg] * inv);
        *(uint2*)&Oattn[bbase + (long)gq * 512 + h * 64 + dm * 16 + qd * 4] = *(uint2*)&ob;
      }
    }
  }
}

// ---------------- launch ----------------
extern "C" void kernel_launch(void* const* d_in, const int* in_sizes, int n_in,
                              void* d_out, int out_size, void* d_ws, size_t ws_size,
                              hipStream_t stream) {
  const float* x  = (const float*)d_in[0];
  const float* Wq = (const float*)d_in[1];
  const float* Wk = (const float*)d_in[2];
  const float* Wv = (const float*)d_in[3];
  const float* Wo = (const float*)d_in[4];
  const float* bo = (const float*)d_in[5];
  float* out = (float*)d_out;

  u16* ws  = (u16*)d_ws;
  u16* Qb  = ws;
  u16* Kb  = Qb  + 4194304;
  u16* Vtg = Kb  + 4194304;   // V^T: [2*512][4096]
  u16* Ab  = Vtg + 4194304;

  dim3 g1(64, 4, 3);
  gemm_qkv_kernel<<<g1, 256, 0, stream>>>(x, Wq, Wk, Wv, Qb, Kb, Vtg);

  dim3 g2(32, 16);
  attn_kernel<<<g2, 256, 0, stream>>>(Qb, Kb, Vtg, Ab);

  dim3 g3(128, 4);
  gemm_out_kernel<<<g3, 256, 0, stream>>>(Ab, Wo, out, bo);
}